// Round 25
// baseline (146.522 us; speedup 1.0000x reference)
//
#include <hip/hip_runtime.h>

typedef unsigned short u16;
typedef float f32x4 __attribute__((ext_vector_type(4)));
typedef __bf16 bf16x8 __attribute__((ext_vector_type(8)));

__device__ __forceinline__ u16 f2bf(float f) {
  union { float f; unsigned u; } v; v.f = f;
  unsigned r = (v.u + 0x7fffu + ((v.u >> 16) & 1u)) >> 16;
  return (u16)r;
}
__device__ __forceinline__ float bf2f(u16 h) {
  union { unsigned u; float f; } v; v.u = ((unsigned)h) << 16; return v.f;
}

#define GLOAD16(gp, lp)                                                        \
  __builtin_amdgcn_global_load_lds(                                            \
      (const __attribute__((address_space(1))) void*)(gp),                     \
      (__attribute__((address_space(3))) void*)(lp), 16, 0, 0)

#define LOG2E 1.4426950408889634f
#define HS 1048576   // per-head plane: 32768 rows * 32

// ------------- fat pre-kernel (r19-verbatim): LN(msa) ++ wfrag ++ wobf ++ pair-LN
__global__ __launch_bounds__(256) void pre_kernel(
    const float* __restrict__ x, const float* __restrict__ sc,
    const float* __restrict__ bi, u16* __restrict__ mo,
    const float* __restrict__ wq, const float* __restrict__ wk,
    const float* __restrict__ wv, const float* __restrict__ wg,
    const float* __restrict__ wo, u16* __restrict__ wfrag, u16* __restrict__ wobf,
    const float* __restrict__ pair, const float* __restrict__ scz,
    const float* __restrict__ biz, const float* __restrict__ wb,
    u16* __restrict__ biasQ)
{
  __shared__ float swc[1024];
  __shared__ float sA[8], sB2[8];
  const int tid = threadIdx.x;

  if (blockIdx.x < 8192) {
    const int row  = blockIdx.x * 4 + (tid >> 6);
    const int lane = tid & 63;
    const float4 v = *(const float4*)(x + (size_t)row * 256 + lane * 4);
    float s = v.x + v.y + v.z + v.w;
    #pragma unroll
    for (int off = 1; off < 64; off <<= 1) s += __shfl_xor(s, off);
    const float mu = s * 0.00390625f;
    const float d0 = v.x - mu, d1 = v.y - mu, d2 = v.z - mu, d3 = v.w - mu;
    float vs = d0*d0 + d1*d1 + d2*d2 + d3*d3;
    #pragma unroll
    for (int off = 1; off < 64; off <<= 1) vs += __shfl_xor(vs, off);
    const float rstd = rsqrtf(vs * 0.00390625f + 1e-5f);
    const float4 scv = *(const float4*)(sc + lane * 4);
    const float4 biv = *(const float4*)(bi + lane * 4);
    ushort4 o;
    o.x = f2bf(d0 * rstd * scv.x + biv.x);
    o.y = f2bf(d1 * rstd * scv.y + biv.y);
    o.z = f2bf(d2 * rstd * scv.z + biv.z);
    o.w = f2bf(d3 * rstd * scv.w + biv.w);
    *(ushort4*)(mo + (size_t)row * 256 + lane * 4) = o;
  } else if (blockIdx.x < 9216) {
    const int d4 = (blockIdx.x - 8192) * 256 + tid;   // 4 elems each
    const int e0 = (d4 & 1) * 4;
    const int lane = (d4 >> 1) & 63;
    const int n  = (d4 >> 7) & 1;
    const int W  = (d4 >> 8) & 3;
    const int kk = (d4 >> 10) & 7;
    const int h  = (d4 >> 13) & 7;
    const float* src = (W == 0) ? wq : (W == 1) ? wk : (W == 2) ? wv : wg;
    const int row = h * 32 + n * 16 + (lane & 15);
    const int col = kk * 32 + (lane >> 4) * 8 + e0;
    float4 v = *(const float4*)(src + (size_t)row * 256 + col);
    ushort4 o;
    o.x = f2bf(v.x); o.y = f2bf(v.y); o.z = f2bf(v.z); o.w = f2bf(v.w);
    *(ushort4*)(wfrag + ((((((size_t)h * 8 + kk) * 4 + W) * 2 + n) * 64 + lane) * 8 + e0)) = o;
  } else if (blockIdx.x < 9280) {
    int e = ((blockIdx.x - 9216) * 256 + tid) * 4;
    int row = e >> 8, col = e & 255;
    float4 v = *(const float4*)(wo + (size_t)row * 256 + col);
    ushort4 o;
    o.x = f2bf(v.x); o.y = f2bf(v.y); o.z = f2bf(v.z); o.w = f2bf(v.w);
    *(ushort4*)(wobf + e) = o;
  } else {
    #pragma unroll
    for (int k = 0; k < 4; ++k) {
      int idx = k * 256 + tid;      // idx = c*8 + h
      int c = idx >> 3, h = idx & 7;
      swc[idx] = scz[c] * wb[h * 128 + c];
    }
    __syncthreads();
    if (tid < 8) {
      float a = 0.f, b2 = 0.f;
      for (int c = 0; c < 128; ++c) {
        a  += swc[c * 8 + tid];
        b2 += biz[c] * wb[tid * 128 + c];
      }
      sA[tid] = a; sB2[tid] = b2;
    }
    __syncthreads();
    const int gt = (blockIdx.x - 9280) * 256 + tid;
    const int ij = gt >> 1, hg = gt & 1;
    const float* xr = pair + (size_t)ij * 128;
    float s = 0.f, ss = 0.f;
    float d0 = 0.f, d1 = 0.f, d2 = 0.f, d3 = 0.f;
    for (int c0 = 0; c0 < 128; c0 += 4) {
      float4 xv4 = *(const float4*)(xr + c0);
      float xe[4] = {xv4.x, xv4.y, xv4.z, xv4.w};
      #pragma unroll
      for (int e = 0; e < 4; ++e) {
        const float xv = xe[e];
        s += xv; ss += xv * xv;
        const f32x4 wv = *(const f32x4*)&swc[(c0 + e) * 8 + hg * 4];
        d0 += xv * wv[0]; d1 += xv * wv[1];
        d2 += xv * wv[2]; d3 += xv * wv[3];
      }
    }
    const float mu = s * 0.0078125f;
    const float rstd = rsqrtf(ss * 0.0078125f - mu * mu + 1e-5f);
    const int i = ij >> 8, j = ij & 255;
    const float dd[4] = {d0, d1, d2, d3};
    #pragma unroll
    for (int hh = 0; hh < 4; ++hh) {
      const int h = hg * 4 + hh;
      const float bias = (dd[hh] - mu * sA[h]) * rstd + sB2[h];
      biasQ[h * 65536 + i * 256 + j] = f2bf(bias * LOG2E);
    }
  }
}

// --------------- FUSED QKV + gate + attention (r23 base + setprio also on
// PROJ MFMA groups — single-variable experiment; attn setprio as r23)
__global__ __launch_bounds__(512) void qkv_attn_kernel(
    const u16* __restrict__ A, const u16* __restrict__ wfrag,
    const float* __restrict__ bgate, const u16* __restrict__ biasQ,
    u16* __restrict__ gatebh, u16* __restrict__ attn_oh)
{
  __shared__ u16 Qlds[256 * 40];   // 20 KB
  __shared__ u16 Klds[256 * 40];   // 20 KB
  __shared__ u16 sVt[32 * 264];    // 16.5 KB (r13/r19-verified layout)
  const int tid = threadIdx.x, lane = tid & 63, w = tid >> 6;
  const int g = lane >> 4, r15 = lane & 15;
  const int h = blockIdx.x & 7;    // head == XCD
  const int b = blockIdx.x >> 3;
  const size_t rowbase = (size_t)b * 256;

  // A fragments: each wave owns rows w*32 .. w*32+31 (loaded ONCE)
  bf16x8 af[2][8];
  #pragma unroll
  for (int m = 0; m < 2; ++m) {
    const size_t arow = rowbase + w * 32 + m * 16 + r15;
    #pragma unroll
    for (int kk = 0; kk < 8; ++kk)
      af[m][kk] = *(const bf16x8*)(A + arow * 256 + kk * 32 + g * 8);
  }

  const u16* wfh = wfrag + (size_t)h * 32768;

  #define PROJ(Wi, ACC)                                                        \
    {                                                                          \
      _Pragma("unroll")                                                        \
      for (int m = 0; m < 2; ++m)                                              \
        _Pragma("unroll")                                                      \
        for (int n = 0; n < 2; ++n) ACC[m][n] = (f32x4){0.f, 0.f, 0.f, 0.f};   \
      _Pragma("unroll")                                                        \
      for (int kk = 0; kk < 8; ++kk) {                                         \
        bf16x8 wf0 = *(const bf16x8*)(wfh + ((kk * 4 + Wi) * 2 + 0) * 512 + lane * 8); \
        bf16x8 wf1 = *(const bf16x8*)(wfh + ((kk * 4 + Wi) * 2 + 1) * 512 + lane * 8); \
        __builtin_amdgcn_s_setprio(1);                                         \
        _Pragma("unroll")                                                      \
        for (int m = 0; m < 2; ++m) {                                          \
          ACC[m][0] = __builtin_amdgcn_mfma_f32_16x16x32_bf16(wf0, af[m][kk], ACC[m][0], 0, 0, 0); \
          ACC[m][1] = __builtin_amdgcn_mfma_f32_16x16x32_bf16(wf1, af[m][kk], ACC[m][1], 0, 0, 0); \
        }                                                                      \
        __builtin_amdgcn_s_setprio(0);                                         \
      }                                                                        \
    }
  // C-layout (swapped): lane holds C[row = w*32+m*16+r15][col = n*16+g*4+rr]

  f32x4 acc[2][2];

  // ---- Q (scaled) -> Qlds (own-wave rows; attention reads only own rows)
  PROJ(0, acc);
  #pragma unroll
  for (int m = 0; m < 2; ++m)
    #pragma unroll
    for (int n = 0; n < 2; ++n) {
      ushort4 o;
      o.x = f2bf(acc[m][n][0] * (0.17677669529663687f * LOG2E));
      o.y = f2bf(acc[m][n][1] * (0.17677669529663687f * LOG2E));
      o.z = f2bf(acc[m][n][2] * (0.17677669529663687f * LOG2E));
      o.w = f2bf(acc[m][n][3] * (0.17677669529663687f * LOG2E));
      *(ushort4*)&Qlds[(w * 32 + m * 16 + r15) * 40 + n * 16 + g * 4] = o;
    }

  // ---- K -> Klds
  PROJ(1, acc);
  #pragma unroll
  for (int m = 0; m < 2; ++m)
    #pragma unroll
    for (int n = 0; n < 2; ++n) {
      ushort4 o;
      o.x = f2bf(acc[m][n][0]); o.y = f2bf(acc[m][n][1]);
      o.z = f2bf(acc[m][n][2]); o.w = f2bf(acc[m][n][3]);
      *(ushort4*)&Klds[(w * 32 + m * 16 + r15) * 40 + n * 16 + g * 4] = o;
    }

  // ---- V -> sVt (permuted key order, r19-verified pos)
  PROJ(2, acc);
  #pragma unroll
  for (int m = 0; m < 2; ++m) {
    const int pos = (w >> 1) * 64 + (w & 1) * 32 + (r15 >> 2) * 8 + m * 4 + (r15 & 3);
    #pragma unroll
    for (int n = 0; n < 2; ++n)
      #pragma unroll
      for (int jj = 0; jj < 4; ++jj)
        sVt[(n * 16 + g * 4 + jj) * 264 + pos] = f2bf(acc[m][n][jj]);
  }

  // ---- gate: PROJ -> sigmoid -> packed in regs (stored AFTER attention)
  PROJ(3, acc);
  ushort4 gpk[2][2];
  {
    #pragma unroll
    for (int m = 0; m < 2; ++m)
      #pragma unroll
      for (int n = 0; n < 2; ++n) {
        const f32x4 gb = *(const f32x4*)(bgate + h * 32 + n * 16 + g * 4);
        gpk[m][n].x = f2bf(1.0f / (1.0f + __expf(-(acc[m][n][0] + gb[0]))));
        gpk[m][n].y = f2bf(1.0f / (1.0f + __expf(-(acc[m][n][1] + gb[1]))));
        gpk[m][n].z = f2bf(1.0f / (1.0f + __expf(-(acc[m][n][2] + gb[2]))));
        gpk[m][n].w = f2bf(1.0f / (1.0f + __expf(-(acc[m][n][3] + gb[3]))));
      }
  }
  __syncthreads();   // the ONLY barrier: K/V visible to all waves

  // ===== attention (r23-verbatim core: setprio on QK/PV clusters) ===========
  const int qrel0 = w * 32 + r15;
  bf16x8 qf[2];
  #pragma unroll
  for (int m = 0; m < 2; ++m)
    qf[m] = *(const bf16x8*)&Qlds[(qrel0 + m * 16) * 40 + g * 8];

  f32x4 oacc[2][2] = {};
  float lrun[2] = {0.f, 0.f};
  const u16* biasH = biasQ + (size_t)h * 65536;

  ushort4 bvu[2][4];
  #pragma unroll
  for (int m = 0; m < 2; ++m)
    #pragma unroll
    for (int n = 0; n < 4; ++n)
      bvu[m][n] = *(const ushort4*)(biasH + (size_t)(qrel0 + m * 16) * 256 + n * 16 + g * 4);

  for (int jb = 0; jb < 4; ++jb) {
    bf16x8 kf[4];
    #pragma unroll
    for (int n = 0; n < 4; ++n)
      kf[n] = *(const bf16x8*)&Klds[(jb * 64 + n * 16 + r15) * 40 + g * 8];
    f32x4 s[2][4];
    __builtin_amdgcn_s_setprio(1);
    #pragma unroll
    for (int m = 0; m < 2; ++m) {
      #pragma unroll
      for (int n = 0; n < 4; ++n) {
        f32x4 z = {0.f, 0.f, 0.f, 0.f};
        s[m][n] = __builtin_amdgcn_mfma_f32_16x16x32_bf16(kf[n], qf[m], z, 0, 0, 0);
      }
    }
    __builtin_amdgcn_s_setprio(0);
    #pragma unroll
    for (int m = 0; m < 2; ++m) {
      #pragma unroll
      for (int n = 0; n < 4; ++n) {
        const u16* bb = (const u16*)&bvu[m][n];
        #pragma unroll
        for (int rr = 0; rr < 4; ++rr) s[m][n][rr] += bf2f(bb[rr]);
      }
    }
    if (jb < 3) {
      const int j1 = jb + 1;
      #pragma unroll
      for (int m = 0; m < 2; ++m)
        #pragma unroll
        for (int n = 0; n < 4; ++n)
          bvu[m][n] = *(const ushort4*)(biasH + (size_t)(qrel0 + m * 16) * 256 + j1 * 64 + n * 16 + g * 4);
    }
    #pragma unroll
    for (int m = 0; m < 2; ++m)
      #pragma unroll
      for (int n = 0; n < 4; ++n)
        #pragma unroll
        for (int rr = 0; rr < 4; ++rr) {
          float p = __builtin_amdgcn_exp2f(s[m][n][rr]);
          s[m][n][rr] = p;
          lrun[m] += p;
        }
    #pragma unroll
    for (int kb = 0; kb < 2; ++kb) {
      bf16x8 vt[2];
      #pragma unroll
      for (int nd = 0; nd < 2; ++nd)
        vt[nd] = *(const bf16x8*)&sVt[(nd * 16 + r15) * 264 + jb * 64 + kb * 32 + g * 8];
      __builtin_amdgcn_s_setprio(1);
      #pragma unroll
      for (int m = 0; m < 2; ++m) {
        bf16x8 pv;
        #pragma unroll
        for (int rr = 0; rr < 4; ++rr) {
          pv[rr]     = (__bf16)s[m][2 * kb][rr];
          pv[4 + rr] = (__bf16)s[m][2 * kb + 1][rr];
        }
        #pragma unroll
        for (int nd = 0; nd < 2; ++nd)
          oacc[m][nd] = __builtin_amdgcn_mfma_f32_16x16x32_bf16(pv, vt[nd], oacc[m][nd], 0, 0, 0);
      }
      __builtin_amdgcn_s_setprio(0);
    }
  }

  #pragma unroll
  for (int m = 0; m < 2; ++m) {
    float l = lrun[m];
    l += __shfl_xor(l, 16);
    l += __shfl_xor(l, 32);
    const float inv = 1.0f / l;
    #pragma unroll
    for (int rr = 0; rr < 4; ++rr) {
      const float invq = __shfl(inv, g * 4 + rr);
      const size_t qrow = rowbase + w * 32 + m * 16 + g * 4 + rr;
      #pragma unroll
      for (int nd = 0; nd < 2; ++nd)
        attn_oh[(size_t)h * HS + qrow * 32 + nd * 16 + r15] = f2bf(oacc[m][nd][rr] * invq);
    }
  }

  // ---- gate stores last (overlap with block drain / next block prologue)
  #pragma unroll
  for (int m = 0; m < 2; ++m) {
    const size_t grow = rowbase + w * 32 + m * 16 + r15;
    #pragma unroll
    for (int n = 0; n < 2; ++n)
      *(ushort4*)(gatebh + (size_t)h * HS + grow * 32 + n * 16 + g * 4) = gpk[m][n];
  }
}

// ----------------------------------------------- EPI1 GEMM (r19-verbatim)
__global__ __launch_bounds__(256, 4) void gemm_epi1(
    const u16* __restrict__ attn_oh, const u16* __restrict__ B,
    const u16* __restrict__ gatebh, float* __restrict__ Cf,
    const float* __restrict__ msa, const float* __restrict__ bout)
{
  __shared__ u16 sB[64 * 256];
  const int tid = threadIdx.x, lane = tid & 63, w = tid >> 6;
  const int g = lane >> 4, r15 = lane & 15;
  const int x = blockIdx.x & 7;
  const int j = blockIdx.x >> 3;
  const int cg = j % 4;
  const int rpl = j / 4;
  const int bcol = cg * 64;

  #pragma unroll
  for (int i = 0; i < 8; ++i) {
    int c = i * 256 + tid;
    int col = c >> 5, s = c & 31;
    int lc = (s & 24) | ((s ^ col) & 7);
    GLOAD16(B + (size_t)(bcol + col) * 256 + lc * 8, &sB[c * 8]);
  }

  float bo[4];
  #pragma unroll
  for (int n = 0; n < 4; ++n) bo[n] = bout[bcol + n * 16 + r15];

  const size_t brow = ((size_t)(x * 32) + rpl) * 128;
  bf16x8 af[2][8];
  #pragma unroll
  for (int m = 0; m < 2; ++m) {
    const size_t arow = brow + w * 32 + m * 16 + r15;
    #pragma unroll
    for (int kk = 0; kk < 8; ++kk)
      af[m][kk] = *(const bf16x8*)(attn_oh + (size_t)kk * HS + arow * 32 + g * 8);
  }
  __syncthreads();

  f32x4 acc[2][4] = {};
  #pragma unroll
  for (int kk = 0; kk < 8; ++kk) {
    bf16x8 bfr[4];
    #pragma unroll
    for (int n = 0; n < 4; ++n) {
      int col = n * 16 + r15;
      int lcq = kk * 4 + g;
      int s = (lcq & 24) | ((lcq ^ col) & 7);
      bfr[n] = *(const bf16x8*)&sB[col * 256 + s * 8];
    }
    #pragma unroll
    for (int m = 0; m < 2; ++m)
      #pragma unroll
      for (int n = 0; n < 4; ++n)
        acc[m][n] = __builtin_amdgcn_mfma_f32_16x16x32_bf16(af[m][kk], bfr[n], acc[m][n], 0, 0, 0);
  }

  #pragma unroll
  for (int m = 0; m < 2; ++m) {
    const int row0 = (int)brow + w * 32 + m * 16 + g * 4;
    #pragma unroll
    for (int n = 0; n < 4; ++n) {
      const int col = bcol + n * 16 + r15;
      #pragma unroll
      for (int rr = 0; rr < 4; ++rr) {
        float v = acc[m][n][rr] + bo[n];
        const size_t orow = (size_t)(row0 + rr);
        float gg = bf2f(gatebh[(size_t)(col >> 5) * HS + orow * 32 + (col & 31)]);
        Cf[orow * 256 + col] = msa[orow * 256 + col] + gg * v;
      }
    }
  }
}

// ------------------------------------------------------------------- launcher
extern "C" void kernel_launch(void* const* d_in, const int* in_sizes, int n_in,
                              void* d_out, int out_size, void* d_ws, size_t ws_size,
                              hipStream_t stream)
{
  (void)in_sizes; (void)n_in; (void)out_size; (void)ws_size;
  const float* msa        = (const float*)d_in[0];
  const float* pair       = (const float*)d_in[1];
  const float* ln_m_scale = (const float*)d_in[2];
  const float* ln_m_bias  = (const float*)d_in[3];
  const float* ln_z_scale = (const float*)d_in[4];
  const float* ln_z_bias  = (const float*)d_in[5];
  const float* w_q        = (const float*)d_in[6];
  const float* w_k        = (const float*)d_in[7];
  const float* w_v        = (const float*)d_in[8];
  const float* w_b        = (const float*)d_in[9];
  const float* w_out      = (const float*)d_in[10];
  const float* b_out      = (const float*)d_in[11];
  const float* w_gate     = (const float*)d_in[12];
  const float* b_gate     = (const float*)d_in[13];

  char* ws = (char*)d_ws;
  u16*   m_bf    = (u16*)(ws);                   // 32768*256 bf16   = 16 MB
  u16*   wobf    = (u16*)(ws + 16777216);        // 128 KB
  u16*   wfrag   = (u16*)(ws + 16908288);        // 512 KB
  u16*   gatebh  = (u16*)(ws + 17432576);        // 16 MB
  u16*   biasQ   = (u16*)(ws + 34209792);        // 1 MB
  u16*   attn_oh = (u16*)(ws + 35258368);        // 16 MB
  float* out = (float*)d_out;

  pre_kernel<<<dim3(9792), dim3(256), 0, stream>>>(
      msa, ln_m_scale, ln_m_bias, m_bf, w_q, w_k, w_v, w_gate, w_out, wfrag, wobf,
      pair, ln_z_scale, ln_z_bias, w_b, biasQ);
  qkv_attn_kernel<<<dim3(1024), dim3(512), 0, stream>>>(
      m_bf, wfrag, b_gate, biasQ, gatebh, attn_oh);
  gemm_epi1<<<dim3(1024), dim3(256), 0, stream>>>(attn_oh, wobf, gatebh, out, msa, b_out);
}

// Round 26
// 129.679 us; speedup vs baseline: 1.1299x; 1.1299x over previous
//
#include <hip/hip_runtime.h>

typedef unsigned short u16;
typedef float f32x4 __attribute__((ext_vector_type(4)));
typedef __bf16 bf16x8 __attribute__((ext_vector_type(8)));

__device__ __forceinline__ u16 f2bf(float f) {
  union { float f; unsigned u; } v; v.f = f;
  unsigned r = (v.u + 0x7fffu + ((v.u >> 16) & 1u)) >> 16;
  return (u16)r;
}
__device__ __forceinline__ float bf2f(u16 h) {
  union { unsigned u; float f; } v; v.u = ((unsigned)h) << 16; return v.f;
}

#define GLOAD16(gp, lp)                                                        \
  __builtin_amdgcn_global_load_lds(                                            \
      (const __attribute__((address_space(1))) void*)(gp),                     \
      (__attribute__((address_space(3))) void*)(lp), 16, 0, 0)

#define LOG2E 1.4426950408889634f
#define HS 1048576   // per-head plane: 32768 rows * 32

// ------------- fat pre-kernel: LN(msa) ++ wfrag cast ++ wobf cast ++ pair-LN
__global__ __launch_bounds__(256) void pre_kernel(
    const float* __restrict__ x, const float* __restrict__ sc,
    const float* __restrict__ bi, u16* __restrict__ mo,
    const float* __restrict__ wq, const float* __restrict__ wk,
    const float* __restrict__ wv, const float* __restrict__ wg,
    const float* __restrict__ wo, u16* __restrict__ wfrag, u16* __restrict__ wobf,
    const float* __restrict__ pair, const float* __restrict__ scz,
    const float* __restrict__ biz, const float* __restrict__ wb,
    u16* __restrict__ biasQ)
{
  __shared__ float swc[1024];
  __shared__ float sA[8], sB2[8];
  const int tid = threadIdx.x;

  if (blockIdx.x < 8192) {
    const int row  = blockIdx.x * 4 + (tid >> 6);
    const int lane = tid & 63;
    const float4 v = *(const float4*)(x + (size_t)row * 256 + lane * 4);
    float s = v.x + v.y + v.z + v.w;
    #pragma unroll
    for (int off = 1; off < 64; off <<= 1) s += __shfl_xor(s, off);
    const float mu = s * 0.00390625f;
    const float d0 = v.x - mu, d1 = v.y - mu, d2 = v.z - mu, d3 = v.w - mu;
    float vs = d0*d0 + d1*d1 + d2*d2 + d3*d3;
    #pragma unroll
    for (int off = 1; off < 64; off <<= 1) vs += __shfl_xor(vs, off);
    const float rstd = rsqrtf(vs * 0.00390625f + 1e-5f);
    const float4 scv = *(const float4*)(sc + lane * 4);
    const float4 biv = *(const float4*)(bi + lane * 4);
    ushort4 o;
    o.x = f2bf(d0 * rstd * scv.x + biv.x);
    o.y = f2bf(d1 * rstd * scv.y + biv.y);
    o.z = f2bf(d2 * rstd * scv.z + biv.z);
    o.w = f2bf(d3 * rstd * scv.w + biv.w);
    *(ushort4*)(mo + (size_t)row * 256 + lane * 4) = o;
  } else if (blockIdx.x < 9216) {
    const int d4 = (blockIdx.x - 8192) * 256 + tid;   // 4 elems each
    const int e0 = (d4 & 1) * 4;
    const int lane = (d4 >> 1) & 63;
    const int n  = (d4 >> 7) & 1;
    const int W  = (d4 >> 8) & 3;
    const int kk = (d4 >> 10) & 7;
    const int h  = (d4 >> 13) & 7;
    const float* src = (W == 0) ? wq : (W == 1) ? wk : (W == 2) ? wv : wg;
    const int row = h * 32 + n * 16 + (lane & 15);
    const int col = kk * 32 + (lane >> 4) * 8 + e0;
    float4 v = *(const float4*)(src + (size_t)row * 256 + col);
    ushort4 o;
    o.x = f2bf(v.x); o.y = f2bf(v.y); o.z = f2bf(v.z); o.w = f2bf(v.w);
    *(ushort4*)(wfrag + ((((((size_t)h * 8 + kk) * 4 + W) * 2 + n) * 64 + lane) * 8 + e0)) = o;
  } else if (blockIdx.x < 9280) {
    int e = ((blockIdx.x - 9216) * 256 + tid) * 4;
    int row = e >> 8, col = e & 255;
    float4 v = *(const float4*)(wo + (size_t)row * 256 + col);
    ushort4 o;
    o.x = f2bf(v.x); o.y = f2bf(v.y); o.z = f2bf(v.z); o.w = f2bf(v.w);
    *(ushort4*)(wobf + e) = o;
  } else {
    #pragma unroll
    for (int k = 0; k < 4; ++k) {
      int idx = k * 256 + tid;      // idx = c*8 + h
      int c = idx >> 3, h = idx & 7;
      swc[idx] = scz[c] * wb[h * 128 + c];
    }
    __syncthreads();
    if (tid < 8) {
      float a = 0.f, b2 = 0.f;
      for (int c = 0; c < 128; ++c) {
        a  += swc[c * 8 + tid];
        b2 += biz[c] * wb[tid * 128 + c];
      }
      sA[tid] = a; sB2[tid] = b2;
    }
    __syncthreads();
    const int gt = (blockIdx.x - 9280) * 256 + tid;
    const int ij = gt >> 1, hg = gt & 1;
    const float* xr = pair + (size_t)ij * 128;
    float s = 0.f, ss = 0.f;
    float d0 = 0.f, d1 = 0.f, d2 = 0.f, d3 = 0.f;
    for (int c0 = 0; c0 < 128; c0 += 4) {
      float4 xv4 = *(const float4*)(xr + c0);
      float xe[4] = {xv4.x, xv4.y, xv4.z, xv4.w};
      #pragma unroll
      for (int e = 0; e < 4; ++e) {
        const float xv = xe[e];
        s += xv; ss += xv * xv;
        const f32x4 wv = *(const f32x4*)&swc[(c0 + e) * 8 + hg * 4];
        d0 += xv * wv[0]; d1 += xv * wv[1];
        d2 += xv * wv[2]; d3 += xv * wv[3];
      }
    }
    const float mu = s * 0.0078125f;
    const float rstd = rsqrtf(ss * 0.0078125f - mu * mu + 1e-5f);
    const int i = ij >> 8, j = ij & 255;
    const float dd[4] = {d0, d1, d2, d3};
    #pragma unroll
    for (int hh = 0; hh < 4; ++hh) {
      const int h = hg * 4 + hh;
      const float bias = (dd[hh] - mu * sA[h]) * rstd + sB2[h];
      biasQ[h * 65536 + i * 256 + j] = f2bf(bias * LOG2E);
    }
  }
}

// --------------- FUSED QKV + gate + attention (r23 champion, FINAL)
// Order: Q->Qlds (OWN-wave rows: no barrier needed), K->Klds, V->sVt,
// gate PROJ -> sigmoid packed in regs, ONE barrier, attention (setprio on
// QK/PV MFMA clusters — the proven +7%), output, gate stores LAST.
__global__ __launch_bounds__(512) void qkv_attn_kernel(
    const u16* __restrict__ A, const u16* __restrict__ wfrag,
    const float* __restrict__ bgate, const u16* __restrict__ biasQ,
    u16* __restrict__ gatebh, u16* __restrict__ attn_oh)
{
  __shared__ u16 Qlds[256 * 40];   // 20 KB
  __shared__ u16 Klds[256 * 40];   // 20 KB
  __shared__ u16 sVt[32 * 264];    // 16.5 KB (r13/r19-verified layout)
  const int tid = threadIdx.x, lane = tid & 63, w = tid >> 6;
  const int g = lane >> 4, r15 = lane & 15;
  const int h = blockIdx.x & 7;    // head == XCD
  const int b = blockIdx.x >> 3;
  const size_t rowbase = (size_t)b * 256;

  // A fragments: each wave owns rows w*32 .. w*32+31 (loaded ONCE)
  bf16x8 af[2][8];
  #pragma unroll
  for (int m = 0; m < 2; ++m) {
    const size_t arow = rowbase + w * 32 + m * 16 + r15;
    #pragma unroll
    for (int kk = 0; kk < 8; ++kk)
      af[m][kk] = *(const bf16x8*)(A + arow * 256 + kk * 32 + g * 8);
  }

  const u16* wfh = wfrag + (size_t)h * 32768;

  #define PROJ(Wi, ACC)                                                        \
    {                                                                          \
      _Pragma("unroll")                                                        \
      for (int m = 0; m < 2; ++m)                                              \
        _Pragma("unroll")                                                      \
        for (int n = 0; n < 2; ++n) ACC[m][n] = (f32x4){0.f, 0.f, 0.f, 0.f};   \
      _Pragma("unroll")                                                        \
      for (int kk = 0; kk < 8; ++kk) {                                         \
        bf16x8 wf0 = *(const bf16x8*)(wfh + ((kk * 4 + Wi) * 2 + 0) * 512 + lane * 8); \
        bf16x8 wf1 = *(const bf16x8*)(wfh + ((kk * 4 + Wi) * 2 + 1) * 512 + lane * 8); \
        _Pragma("unroll")                                                      \
        for (int m = 0; m < 2; ++m) {                                          \
          ACC[m][0] = __builtin_amdgcn_mfma_f32_16x16x32_bf16(wf0, af[m][kk], ACC[m][0], 0, 0, 0); \
          ACC[m][1] = __builtin_amdgcn_mfma_f32_16x16x32_bf16(wf1, af[m][kk], ACC[m][1], 0, 0, 0); \
        }                                                                      \
      }                                                                        \
    }
  // C-layout (swapped): lane holds C[row = w*32+m*16+r15][col = n*16+g*4+rr]

  f32x4 acc[2][2];

  // ---- Q (scaled) -> Qlds (own-wave rows; attention reads only own rows)
  PROJ(0, acc);
  #pragma unroll
  for (int m = 0; m < 2; ++m)
    #pragma unroll
    for (int n = 0; n < 2; ++n) {
      ushort4 o;
      o.x = f2bf(acc[m][n][0] * (0.17677669529663687f * LOG2E));
      o.y = f2bf(acc[m][n][1] * (0.17677669529663687f * LOG2E));
      o.z = f2bf(acc[m][n][2] * (0.17677669529663687f * LOG2E));
      o.w = f2bf(acc[m][n][3] * (0.17677669529663687f * LOG2E));
      *(ushort4*)&Qlds[(w * 32 + m * 16 + r15) * 40 + n * 16 + g * 4] = o;
    }

  // ---- K -> Klds
  PROJ(1, acc);
  #pragma unroll
  for (int m = 0; m < 2; ++m)
    #pragma unroll
    for (int n = 0; n < 2; ++n) {
      ushort4 o;
      o.x = f2bf(acc[m][n][0]); o.y = f2bf(acc[m][n][1]);
      o.z = f2bf(acc[m][n][2]); o.w = f2bf(acc[m][n][3]);
      *(ushort4*)&Klds[(w * 32 + m * 16 + r15) * 40 + n * 16 + g * 4] = o;
    }

  // ---- V -> sVt (permuted key order, r19-verified pos)
  PROJ(2, acc);
  #pragma unroll
  for (int m = 0; m < 2; ++m) {
    const int pos = (w >> 1) * 64 + (w & 1) * 32 + (r15 >> 2) * 8 + m * 4 + (r15 & 3);
    #pragma unroll
    for (int n = 0; n < 2; ++n)
      #pragma unroll
      for (int jj = 0; jj < 4; ++jj)
        sVt[(n * 16 + g * 4 + jj) * 264 + pos] = f2bf(acc[m][n][jj]);
  }

  // ---- gate: PROJ -> sigmoid -> packed in regs (stored AFTER attention)
  PROJ(3, acc);
  ushort4 gpk[2][2];
  {
    #pragma unroll
    for (int m = 0; m < 2; ++m)
      #pragma unroll
      for (int n = 0; n < 2; ++n) {
        const f32x4 gb = *(const f32x4*)(bgate + h * 32 + n * 16 + g * 4);
        gpk[m][n].x = f2bf(1.0f / (1.0f + __expf(-(acc[m][n][0] + gb[0]))));
        gpk[m][n].y = f2bf(1.0f / (1.0f + __expf(-(acc[m][n][1] + gb[1]))));
        gpk[m][n].z = f2bf(1.0f / (1.0f + __expf(-(acc[m][n][2] + gb[2]))));
        gpk[m][n].w = f2bf(1.0f / (1.0f + __expf(-(acc[m][n][3] + gb[3]))));
      }
  }
  __syncthreads();   // the ONLY barrier: K/V visible to all waves

  // ===== attention (setprio on QK/PV clusters — r23-verified +7%) ===========
  const int qrel0 = w * 32 + r15;
  bf16x8 qf[2];
  #pragma unroll
  for (int m = 0; m < 2; ++m)
    qf[m] = *(const bf16x8*)&Qlds[(qrel0 + m * 16) * 40 + g * 8];

  f32x4 oacc[2][2] = {};
  float lrun[2] = {0.f, 0.f};
  const u16* biasH = biasQ + (size_t)h * 65536;

  ushort4 bvu[2][4];
  #pragma unroll
  for (int m = 0; m < 2; ++m)
    #pragma unroll
    for (int n = 0; n < 4; ++n)
      bvu[m][n] = *(const ushort4*)(biasH + (size_t)(qrel0 + m * 16) * 256 + n * 16 + g * 4);

  for (int jb = 0; jb < 4; ++jb) {
    bf16x8 kf[4];
    #pragma unroll
    for (int n = 0; n < 4; ++n)
      kf[n] = *(const bf16x8*)&Klds[(jb * 64 + n * 16 + r15) * 40 + g * 8];
    f32x4 s[2][4];
    __builtin_amdgcn_s_setprio(1);
    #pragma unroll
    for (int m = 0; m < 2; ++m) {
      #pragma unroll
      for (int n = 0; n < 4; ++n) {
        f32x4 z = {0.f, 0.f, 0.f, 0.f};
        s[m][n] = __builtin_amdgcn_mfma_f32_16x16x32_bf16(kf[n], qf[m], z, 0, 0, 0);
      }
    }
    __builtin_amdgcn_s_setprio(0);
    #pragma unroll
    for (int m = 0; m < 2; ++m) {
      #pragma unroll
      for (int n = 0; n < 4; ++n) {
        const u16* bb = (const u16*)&bvu[m][n];
        #pragma unroll
        for (int rr = 0; rr < 4; ++rr) s[m][n][rr] += bf2f(bb[rr]);
      }
    }
    if (jb < 3) {
      const int j1 = jb + 1;
      #pragma unroll
      for (int m = 0; m < 2; ++m)
        #pragma unroll
        for (int n = 0; n < 4; ++n)
          bvu[m][n] = *(const ushort4*)(biasH + (size_t)(qrel0 + m * 16) * 256 + j1 * 64 + n * 16 + g * 4);
    }
    #pragma unroll
    for (int m = 0; m < 2; ++m)
      #pragma unroll
      for (int n = 0; n < 4; ++n)
        #pragma unroll
        for (int rr = 0; rr < 4; ++rr) {
          float p = __builtin_amdgcn_exp2f(s[m][n][rr]);
          s[m][n][rr] = p;
          lrun[m] += p;
        }
    #pragma unroll
    for (int kb = 0; kb < 2; ++kb) {
      bf16x8 vt[2];
      #pragma unroll
      for (int nd = 0; nd < 2; ++nd)
        vt[nd] = *(const bf16x8*)&sVt[(nd * 16 + r15) * 264 + jb * 64 + kb * 32 + g * 8];
      __builtin_amdgcn_s_setprio(1);
      #pragma unroll
      for (int m = 0; m < 2; ++m) {
        bf16x8 pv;
        #pragma unroll
        for (int rr = 0; rr < 4; ++rr) {
          pv[rr]     = (__bf16)s[m][2 * kb][rr];
          pv[4 + rr] = (__bf16)s[m][2 * kb + 1][rr];
        }
        #pragma unroll
        for (int nd = 0; nd < 2; ++nd)
          oacc[m][nd] = __builtin_amdgcn_mfma_f32_16x16x32_bf16(pv, vt[nd], oacc[m][nd], 0, 0, 0);
      }
      __builtin_amdgcn_s_setprio(0);
    }
  }

  #pragma unroll
  for (int m = 0; m < 2; ++m) {
    float l = lrun[m];
    l += __shfl_xor(l, 16);
    l += __shfl_xor(l, 32);
    const float inv = 1.0f / l;
    #pragma unroll
    for (int rr = 0; rr < 4; ++rr) {
      const float invq = __shfl(inv, g * 4 + rr);
      const size_t qrow = rowbase + w * 32 + m * 16 + g * 4 + rr;
      #pragma unroll
      for (int nd = 0; nd < 2; ++nd)
        attn_oh[(size_t)h * HS + qrow * 32 + nd * 16 + r15] = f2bf(oacc[m][nd][rr] * invq);
    }
  }

  // ---- gate stores last (overlap with block drain / next block prologue)
  #pragma unroll
  for (int m = 0; m < 2; ++m) {
    const size_t grow = rowbase + w * 32 + m * 16 + r15;
    #pragma unroll
    for (int n = 0; n < 2; ++n)
      *(ushort4*)(gatebh + (size_t)h * HS + grow * 32 + n * 16 + g * 4) = gpk[m][n];
  }
}

// ----------------------------------------------- EPI1 GEMM (r19-verbatim)
__global__ __launch_bounds__(256, 4) void gemm_epi1(
    const u16* __restrict__ attn_oh, const u16* __restrict__ B,
    const u16* __restrict__ gatebh, float* __restrict__ Cf,
    const float* __restrict__ msa, const float* __restrict__ bout)
{
  __shared__ u16 sB[64 * 256];
  const int tid = threadIdx.x, lane = tid & 63, w = tid >> 6;
  const int g = lane >> 4, r15 = lane & 15;
  const int x = blockIdx.x & 7;
  const int j = blockIdx.x >> 3;
  const int cg = j % 4;
  const int rpl = j / 4;
  const int bcol = cg * 64;

  #pragma unroll
  for (int i = 0; i < 8; ++i) {
    int c = i * 256 + tid;
    int col = c >> 5, s = c & 31;
    int lc = (s & 24) | ((s ^ col) & 7);
    GLOAD16(B + (size_t)(bcol + col) * 256 + lc * 8, &sB[c * 8]);
  }

  float bo[4];
  #pragma unroll
  for (int n = 0; n < 4; ++n) bo[n] = bout[bcol + n * 16 + r15];

  const size_t brow = ((size_t)(x * 32) + rpl) * 128;
  bf16x8 af[2][8];
  #pragma unroll
  for (int m = 0; m < 2; ++m) {
    const size_t arow = brow + w * 32 + m * 16 + r15;
    #pragma unroll
    for (int kk = 0; kk < 8; ++kk)
      af[m][kk] = *(const bf16x8*)(attn_oh + (size_t)kk * HS + arow * 32 + g * 8);
  }
  __syncthreads();

  f32x4 acc[2][4] = {};
  #pragma unroll
  for (int kk = 0; kk < 8; ++kk) {
    bf16x8 bfr[4];
    #pragma unroll
    for (int n = 0; n < 4; ++n) {
      int col = n * 16 + r15;
      int lcq = kk * 4 + g;
      int s = (lcq & 24) | ((lcq ^ col) & 7);
      bfr[n] = *(const bf16x8*)&sB[col * 256 + s * 8];
    }
    #pragma unroll
    for (int m = 0; m < 2; ++m)
      #pragma unroll
      for (int n = 0; n < 4; ++n)
        acc[m][n] = __builtin_amdgcn_mfma_f32_16x16x32_bf16(af[m][kk], bfr[n], acc[m][n], 0, 0, 0);
  }

  #pragma unroll
  for (int m = 0; m < 2; ++m) {
    const int row0 = (int)brow + w * 32 + m * 16 + g * 4;
    #pragma unroll
    for (int n = 0; n < 4; ++n) {
      const int col = bcol + n * 16 + r15;
      #pragma unroll
      for (int rr = 0; rr < 4; ++rr) {
        float v = acc[m][n][rr] + bo[n];
        const size_t orow = (size_t)(row0 + rr);
        float gg = bf2f(gatebh[(size_t)(col >> 5) * HS + orow * 32 + (col & 31)]);
        Cf[orow * 256 + col] = msa[orow * 256 + col] + gg * v;
      }
    }
  }
}

// ------------------------------------------------------------------- launcher
extern "C" void kernel_launch(void* const* d_in, const int* in_sizes, int n_in,
                              void* d_out, int out_size, void* d_ws, size_t ws_size,
                              hipStream_t stream)
{
  (void)in_sizes; (void)n_in; (void)out_size; (void)ws_size;
  const float* msa        = (const float*)d_in[0];
  const float* pair       = (const float*)d_in[1];
  const float* ln_m_scale = (const float*)d_in[2];
  const float* ln_m_bias  = (const float*)d_in[3];
  const float* ln_z_scale = (const float*)d_in[4];
  const float* ln_z_bias  = (const float*)d_in[5];
  const float* w_q        = (const float*)d_in[6];
  const float* w_k        = (const float*)d_in[7];
  const float* w_v        = (const float*)d_in[8];
  const float* w_b        = (const float*)d_in[9];
  const float* w_out      = (const float*)d_in[10];
  const float* b_out      = (const float*)d_in[11];
  const float* w_gate     = (const float*)d_in[12];
  const float* b_gate     = (const float*)d_in[13];

  char* ws = (char*)d_ws;
  u16*   m_bf    = (u16*)(ws);                   // 32768*256 bf16   = 16 MB
  u16*   wobf    = (u16*)(ws + 16777216);        // 128 KB
  u16*   wfrag   = (u16*)(ws + 16908288);        // 512 KB
  u16*   gatebh  = (u16*)(ws + 17432576);        // 16 MB
  u16*   biasQ   = (u16*)(ws + 34209792);        // 1 MB
  u16*   attn_oh = (u16*)(ws + 35258368);        // 16 MB
  float* out = (float*)d_out;

  pre_kernel<<<dim3(9792), dim3(256), 0, stream>>>(
      msa, ln_m_scale, ln_m_bias, m_bf, w_q, w_k, w_v, w_gate, w_out, wfrag, wobf,
      pair, ln_z_scale, ln_z_bias, w_b, biasQ);
  qkv_attn_kernel<<<dim3(1024), dim3(512), 0, stream>>>(
      m_bf, wfrag, b_gate, biasQ, gatebh, attn_oh);
  gemm_epi1<<<dim3(1024), dim3(256), 0, stream>>>(attn_oh, wobf, gatebh, out, msa, b_out);
}

// Round 27
// 128.581 us; speedup vs baseline: 1.1395x; 1.0085x over previous
//
#include <hip/hip_runtime.h>

typedef unsigned short u16;
typedef float f32x4 __attribute__((ext_vector_type(4)));
typedef __bf16 bf16x8 __attribute__((ext_vector_type(8)));

__device__ __forceinline__ u16 f2bf(float f) {
  union { float f; unsigned u; } v; v.f = f;
  unsigned r = (v.u + 0x7fffu + ((v.u >> 16) & 1u)) >> 16;
  return (u16)r;
}
__device__ __forceinline__ float bf2f(u16 h) {
  union { unsigned u; float f; } v; v.u = ((unsigned)h) << 16; return v.f;
}

#define GLOAD16(gp, lp)                                                        \
  __builtin_amdgcn_global_load_lds(                                            \
      (const __attribute__((address_space(1))) void*)(gp),                     \
      (__attribute__((address_space(3))) void*)(lp), 16, 0, 0)

#define LOG2E 1.4426950408889634f
#define HS 1048576   // per-head plane: 32768 rows * 32

// ------------- fat pre-kernel (champion-verbatim): LN(msa) ++ wfrag ++ wobf ++ pair-LN
__global__ __launch_bounds__(256) void pre_kernel(
    const float* __restrict__ x, const float* __restrict__ sc,
    const float* __restrict__ bi, u16* __restrict__ mo,
    const float* __restrict__ wq, const float* __restrict__ wk,
    const float* __restrict__ wv, const float* __restrict__ wg,
    const float* __restrict__ wo, u16* __restrict__ wfrag, u16* __restrict__ wobf,
    const float* __restrict__ pair, const float* __restrict__ scz,
    const float* __restrict__ biz, const float* __restrict__ wb,
    u16* __restrict__ biasQ)
{
  __shared__ float swc[1024];
  __shared__ float sA[8], sB2[8];
  const int tid = threadIdx.x;

  if (blockIdx.x < 8192) {
    const int row  = blockIdx.x * 4 + (tid >> 6);
    const int lane = tid & 63;
    const float4 v = *(const float4*)(x + (size_t)row * 256 + lane * 4);
    float s = v.x + v.y + v.z + v.w;
    #pragma unroll
    for (int off = 1; off < 64; off <<= 1) s += __shfl_xor(s, off);
    const float mu = s * 0.00390625f;
    const float d0 = v.x - mu, d1 = v.y - mu, d2 = v.z - mu, d3 = v.w - mu;
    float vs = d0*d0 + d1*d1 + d2*d2 + d3*d3;
    #pragma unroll
    for (int off = 1; off < 64; off <<= 1) vs += __shfl_xor(vs, off);
    const float rstd = rsqrtf(vs * 0.00390625f + 1e-5f);
    const float4 scv = *(const float4*)(sc + lane * 4);
    const float4 biv = *(const float4*)(bi + lane * 4);
    ushort4 o;
    o.x = f2bf(d0 * rstd * scv.x + biv.x);
    o.y = f2bf(d1 * rstd * scv.y + biv.y);
    o.z = f2bf(d2 * rstd * scv.z + biv.z);
    o.w = f2bf(d3 * rstd * scv.w + biv.w);
    *(ushort4*)(mo + (size_t)row * 256 + lane * 4) = o;
  } else if (blockIdx.x < 9216) {
    const int d4 = (blockIdx.x - 8192) * 256 + tid;   // 4 elems each
    const int e0 = (d4 & 1) * 4;
    const int lane = (d4 >> 1) & 63;
    const int n  = (d4 >> 7) & 1;
    const int W  = (d4 >> 8) & 3;
    const int kk = (d4 >> 10) & 7;
    const int h  = (d4 >> 13) & 7;
    const float* src = (W == 0) ? wq : (W == 1) ? wk : (W == 2) ? wv : wg;
    const int row = h * 32 + n * 16 + (lane & 15);
    const int col = kk * 32 + (lane >> 4) * 8 + e0;
    float4 v = *(const float4*)(src + (size_t)row * 256 + col);
    ushort4 o;
    o.x = f2bf(v.x); o.y = f2bf(v.y); o.z = f2bf(v.z); o.w = f2bf(v.w);
    *(ushort4*)(wfrag + ((((((size_t)h * 8 + kk) * 4 + W) * 2 + n) * 64 + lane) * 8 + e0)) = o;
  } else if (blockIdx.x < 9280) {
    int e = ((blockIdx.x - 9216) * 256 + tid) * 4;
    int row = e >> 8, col = e & 255;
    float4 v = *(const float4*)(wo + (size_t)row * 256 + col);
    ushort4 o;
    o.x = f2bf(v.x); o.y = f2bf(v.y); o.z = f2bf(v.z); o.w = f2bf(v.w);
    *(ushort4*)(wobf + e) = o;
  } else {
    #pragma unroll
    for (int k = 0; k < 4; ++k) {
      int idx = k * 256 + tid;      // idx = c*8 + h
      int c = idx >> 3, h = idx & 7;
      swc[idx] = scz[c] * wb[h * 128 + c];
    }
    __syncthreads();
    if (tid < 8) {
      float a = 0.f, b2 = 0.f;
      for (int c = 0; c < 128; ++c) {
        a  += swc[c * 8 + tid];
        b2 += biz[c] * wb[tid * 128 + c];
      }
      sA[tid] = a; sB2[tid] = b2;
    }
    __syncthreads();
    const int gt = (blockIdx.x - 9280) * 256 + tid;
    const int ij = gt >> 1, hg = gt & 1;
    const float* xr = pair + (size_t)ij * 128;
    float s = 0.f, ss = 0.f;
    float d0 = 0.f, d1 = 0.f, d2 = 0.f, d3 = 0.f;
    for (int c0 = 0; c0 < 128; c0 += 4) {
      float4 xv4 = *(const float4*)(xr + c0);
      float xe[4] = {xv4.x, xv4.y, xv4.z, xv4.w};
      #pragma unroll
      for (int e = 0; e < 4; ++e) {
        const float xv = xe[e];
        s += xv; ss += xv * xv;
        const f32x4 wv = *(const f32x4*)&swc[(c0 + e) * 8 + hg * 4];
        d0 += xv * wv[0]; d1 += xv * wv[1];
        d2 += xv * wv[2]; d3 += xv * wv[3];
      }
    }
    const float mu = s * 0.0078125f;
    const float rstd = rsqrtf(ss * 0.0078125f - mu * mu + 1e-5f);
    const int i = ij >> 8, j = ij & 255;
    const float dd[4] = {d0, d1, d2, d3};
    #pragma unroll
    for (int hh = 0; hh < 4; ++hh) {
      const int h = hg * 4 + hh;
      const float bias = (dd[hh] - mu * sA[h]) * rstd + sB2[h];
      biasQ[h * 65536 + i * 256 + j] = f2bf(bias * LOG2E);
    }
  }
}

// --------------- FUSED QKV + gate + attention (champion-verbatim)
__global__ __launch_bounds__(512) void qkv_attn_kernel(
    const u16* __restrict__ A, const u16* __restrict__ wfrag,
    const float* __restrict__ bgate, const u16* __restrict__ biasQ,
    u16* __restrict__ gatebh, u16* __restrict__ attn_oh)
{
  __shared__ u16 Qlds[256 * 40];   // 20 KB
  __shared__ u16 Klds[256 * 40];   // 20 KB
  __shared__ u16 sVt[32 * 264];    // 16.5 KB (r13/r19-verified layout)
  const int tid = threadIdx.x, lane = tid & 63, w = tid >> 6;
  const int g = lane >> 4, r15 = lane & 15;
  const int h = blockIdx.x & 7;    // head == XCD
  const int b = blockIdx.x >> 3;
  const size_t rowbase = (size_t)b * 256;

  bf16x8 af[2][8];
  #pragma unroll
  for (int m = 0; m < 2; ++m) {
    const size_t arow = rowbase + w * 32 + m * 16 + r15;
    #pragma unroll
    for (int kk = 0; kk < 8; ++kk)
      af[m][kk] = *(const bf16x8*)(A + arow * 256 + kk * 32 + g * 8);
  }

  const u16* wfh = wfrag + (size_t)h * 32768;

  #define PROJ(Wi, ACC)                                                        \
    {                                                                          \
      _Pragma("unroll")                                                        \
      for (int m = 0; m < 2; ++m)                                              \
        _Pragma("unroll")                                                      \
        for (int n = 0; n < 2; ++n) ACC[m][n] = (f32x4){0.f, 0.f, 0.f, 0.f};   \
      _Pragma("unroll")                                                        \
      for (int kk = 0; kk < 8; ++kk) {                                         \
        bf16x8 wf0 = *(const bf16x8*)(wfh + ((kk * 4 + Wi) * 2 + 0) * 512 + lane * 8); \
        bf16x8 wf1 = *(const bf16x8*)(wfh + ((kk * 4 + Wi) * 2 + 1) * 512 + lane * 8); \
        _Pragma("unroll")                                                      \
        for (int m = 0; m < 2; ++m) {                                          \
          ACC[m][0] = __builtin_amdgcn_mfma_f32_16x16x32_bf16(wf0, af[m][kk], ACC[m][0], 0, 0, 0); \
          ACC[m][1] = __builtin_amdgcn_mfma_f32_16x16x32_bf16(wf1, af[m][kk], ACC[m][1], 0, 0, 0); \
        }                                                                      \
      }                                                                        \
    }
  // C-layout (swapped): lane holds C[row = w*32+m*16+r15][col = n*16+g*4+rr]

  f32x4 acc[2][2];

  // ---- Q (scaled) -> Qlds (own-wave rows; attention reads only own rows)
  PROJ(0, acc);
  #pragma unroll
  for (int m = 0; m < 2; ++m)
    #pragma unroll
    for (int n = 0; n < 2; ++n) {
      ushort4 o;
      o.x = f2bf(acc[m][n][0] * (0.17677669529663687f * LOG2E));
      o.y = f2bf(acc[m][n][1] * (0.17677669529663687f * LOG2E));
      o.z = f2bf(acc[m][n][2] * (0.17677669529663687f * LOG2E));
      o.w = f2bf(acc[m][n][3] * (0.17677669529663687f * LOG2E));
      *(ushort4*)&Qlds[(w * 32 + m * 16 + r15) * 40 + n * 16 + g * 4] = o;
    }

  // ---- K -> Klds
  PROJ(1, acc);
  #pragma unroll
  for (int m = 0; m < 2; ++m)
    #pragma unroll
    for (int n = 0; n < 2; ++n) {
      ushort4 o;
      o.x = f2bf(acc[m][n][0]); o.y = f2bf(acc[m][n][1]);
      o.z = f2bf(acc[m][n][2]); o.w = f2bf(acc[m][n][3]);
      *(ushort4*)&Klds[(w * 32 + m * 16 + r15) * 40 + n * 16 + g * 4] = o;
    }

  // ---- V -> sVt (permuted key order, r19-verified pos)
  PROJ(2, acc);
  #pragma unroll
  for (int m = 0; m < 2; ++m) {
    const int pos = (w >> 1) * 64 + (w & 1) * 32 + (r15 >> 2) * 8 + m * 4 + (r15 & 3);
    #pragma unroll
    for (int n = 0; n < 2; ++n)
      #pragma unroll
      for (int jj = 0; jj < 4; ++jj)
        sVt[(n * 16 + g * 4 + jj) * 264 + pos] = f2bf(acc[m][n][jj]);
  }

  // ---- gate: PROJ -> sigmoid -> packed in regs (stored AFTER attention)
  PROJ(3, acc);
  ushort4 gpk[2][2];
  {
    #pragma unroll
    for (int m = 0; m < 2; ++m)
      #pragma unroll
      for (int n = 0; n < 2; ++n) {
        const f32x4 gb = *(const f32x4*)(bgate + h * 32 + n * 16 + g * 4);
        gpk[m][n].x = f2bf(1.0f / (1.0f + __expf(-(acc[m][n][0] + gb[0]))));
        gpk[m][n].y = f2bf(1.0f / (1.0f + __expf(-(acc[m][n][1] + gb[1]))));
        gpk[m][n].z = f2bf(1.0f / (1.0f + __expf(-(acc[m][n][2] + gb[2]))));
        gpk[m][n].w = f2bf(1.0f / (1.0f + __expf(-(acc[m][n][3] + gb[3]))));
      }
  }
  __syncthreads();   // the ONLY barrier: K/V visible to all waves

  // ===== attention (setprio on QK/PV clusters — r23-verified +7%) ===========
  const int qrel0 = w * 32 + r15;
  bf16x8 qf[2];
  #pragma unroll
  for (int m = 0; m < 2; ++m)
    qf[m] = *(const bf16x8*)&Qlds[(qrel0 + m * 16) * 40 + g * 8];

  f32x4 oacc[2][2] = {};
  float lrun[2] = {0.f, 0.f};
  const u16* biasH = biasQ + (size_t)h * 65536;

  ushort4 bvu[2][4];
  #pragma unroll
  for (int m = 0; m < 2; ++m)
    #pragma unroll
    for (int n = 0; n < 4; ++n)
      bvu[m][n] = *(const ushort4*)(biasH + (size_t)(qrel0 + m * 16) * 256 + n * 16 + g * 4);

  for (int jb = 0; jb < 4; ++jb) {
    bf16x8 kf[4];
    #pragma unroll
    for (int n = 0; n < 4; ++n)
      kf[n] = *(const bf16x8*)&Klds[(jb * 64 + n * 16 + r15) * 40 + g * 8];
    f32x4 s[2][4];
    __builtin_amdgcn_s_setprio(1);
    #pragma unroll
    for (int m = 0; m < 2; ++m) {
      #pragma unroll
      for (int n = 0; n < 4; ++n) {
        f32x4 z = {0.f, 0.f, 0.f, 0.f};
        s[m][n] = __builtin_amdgcn_mfma_f32_16x16x32_bf16(kf[n], qf[m], z, 0, 0, 0);
      }
    }
    __builtin_amdgcn_s_setprio(0);
    #pragma unroll
    for (int m = 0; m < 2; ++m) {
      #pragma unroll
      for (int n = 0; n < 4; ++n) {
        const u16* bb = (const u16*)&bvu[m][n];
        #pragma unroll
        for (int rr = 0; rr < 4; ++rr) s[m][n][rr] += bf2f(bb[rr]);
      }
    }
    if (jb < 3) {
      const int j1 = jb + 1;
      #pragma unroll
      for (int m = 0; m < 2; ++m)
        #pragma unroll
        for (int n = 0; n < 4; ++n)
          bvu[m][n] = *(const ushort4*)(biasH + (size_t)(qrel0 + m * 16) * 256 + j1 * 64 + n * 16 + g * 4);
    }
    #pragma unroll
    for (int m = 0; m < 2; ++m)
      #pragma unroll
      for (int n = 0; n < 4; ++n)
        #pragma unroll
        for (int rr = 0; rr < 4; ++rr) {
          float p = __builtin_amdgcn_exp2f(s[m][n][rr]);
          s[m][n][rr] = p;
          lrun[m] += p;
        }
    #pragma unroll
    for (int kb = 0; kb < 2; ++kb) {
      bf16x8 vt[2];
      #pragma unroll
      for (int nd = 0; nd < 2; ++nd)
        vt[nd] = *(const bf16x8*)&sVt[(nd * 16 + r15) * 264 + jb * 64 + kb * 32 + g * 8];
      __builtin_amdgcn_s_setprio(1);
      #pragma unroll
      for (int m = 0; m < 2; ++m) {
        bf16x8 pv;
        #pragma unroll
        for (int rr = 0; rr < 4; ++rr) {
          pv[rr]     = (__bf16)s[m][2 * kb][rr];
          pv[4 + rr] = (__bf16)s[m][2 * kb + 1][rr];
        }
        #pragma unroll
        for (int nd = 0; nd < 2; ++nd)
          oacc[m][nd] = __builtin_amdgcn_mfma_f32_16x16x32_bf16(pv, vt[nd], oacc[m][nd], 0, 0, 0);
      }
      __builtin_amdgcn_s_setprio(0);
    }
  }

  #pragma unroll
  for (int m = 0; m < 2; ++m) {
    float l = lrun[m];
    l += __shfl_xor(l, 16);
    l += __shfl_xor(l, 32);
    const float inv = 1.0f / l;
    #pragma unroll
    for (int rr = 0; rr < 4; ++rr) {
      const float invq = __shfl(inv, g * 4 + rr);
      const size_t qrow = rowbase + w * 32 + m * 16 + g * 4 + rr;
      #pragma unroll
      for (int nd = 0; nd < 2; ++nd)
        attn_oh[(size_t)h * HS + qrow * 32 + nd * 16 + r15] = f2bf(oacc[m][nd][rr] * invq);
    }
  }

  // ---- gate stores last (overlap with block drain / next block prologue)
  #pragma unroll
  for (int m = 0; m < 2; ++m) {
    const size_t grow = rowbase + w * 32 + m * 16 + r15;
    #pragma unroll
    for (int n = 0; n < 2; ++n)
      *(ushort4*)(gatebh + (size_t)h * HS + grow * 32 + n * 16 + g * 4) = gpk[m][n];
  }
}

// ----------------------------------------------- EPI1 GEMM, 256-row tiles
// Single variable vs champion: 512-thread blocks covering 256 rows per B-tile
// (grid 512). Same per-CU wave count (16), but HALF the B-stage chains and
// half B's logical re-read; af loads still issued before the barrier so HBM
// latency hides under the B-stage drain.
__global__ __launch_bounds__(512, 2) void gemm_epi1(
    const u16* __restrict__ attn_oh, const u16* __restrict__ B,
    const u16* __restrict__ gatebh, float* __restrict__ Cf,
    const float* __restrict__ msa, const float* __restrict__ bout)
{
  __shared__ u16 sB[64 * 256];
  const int tid = threadIdx.x, lane = tid & 63, w = tid >> 6;  // w = 0..7
  const int g = lane >> 4, r15 = lane & 15;
  const int x = blockIdx.x & 7;
  const int j = blockIdx.x >> 3;          // 0..63 per XCD
  const int cg = j & 3;
  const int rpl = j >> 2;                 // 0..15
  const int bcol = cg * 64;

  #pragma unroll
  for (int i = 0; i < 4; ++i) {
    int c = i * 512 + tid;                // chunk 0..2047 (16B each)
    int col = c >> 5, s = c & 31;
    int lc = (s & 24) | ((s ^ col) & 7);
    GLOAD16(B + (size_t)(bcol + col) * 256 + lc * 8, &sB[c * 8]);
  }

  float bo[4];
  #pragma unroll
  for (int n = 0; n < 4; ++n) bo[n] = bout[bcol + n * 16 + r15];

  const size_t brow = ((size_t)(x * 16) + rpl) * 256;
  bf16x8 af[2][8];
  #pragma unroll
  for (int m = 0; m < 2; ++m) {
    const size_t arow = brow + w * 32 + m * 16 + r15;
    #pragma unroll
    for (int kk = 0; kk < 8; ++kk)
      af[m][kk] = *(const bf16x8*)(attn_oh + (size_t)kk * HS + arow * 32 + g * 8);
  }
  __syncthreads();

  f32x4 acc[2][4] = {};
  #pragma unroll
  for (int kk = 0; kk < 8; ++kk) {
    bf16x8 bfr[4];
    #pragma unroll
    for (int n = 0; n < 4; ++n) {
      int col = n * 16 + r15;
      int lcq = kk * 4 + g;
      int s = (lcq & 24) | ((lcq ^ col) & 7);
      bfr[n] = *(const bf16x8*)&sB[col * 256 + s * 8];
    }
    #pragma unroll
    for (int m = 0; m < 2; ++m)
      #pragma unroll
      for (int n = 0; n < 4; ++n)
        acc[m][n] = __builtin_amdgcn_mfma_f32_16x16x32_bf16(af[m][kk], bfr[n], acc[m][n], 0, 0, 0);
  }

  #pragma unroll
  for (int m = 0; m < 2; ++m) {
    const int row0 = (int)brow + w * 32 + m * 16 + g * 4;
    #pragma unroll
    for (int n = 0; n < 4; ++n) {
      const int col = bcol + n * 16 + r15;
      #pragma unroll
      for (int rr = 0; rr < 4; ++rr) {
        float v = acc[m][n][rr] + bo[n];
        const size_t orow = (size_t)(row0 + rr);
        float gg = bf2f(gatebh[(size_t)(col >> 5) * HS + orow * 32 + (col & 31)]);
        Cf[orow * 256 + col] = msa[orow * 256 + col] + gg * v;
      }
    }
  }
}

// ------------------------------------------------------------------- launcher
extern "C" void kernel_launch(void* const* d_in, const int* in_sizes, int n_in,
                              void* d_out, int out_size, void* d_ws, size_t ws_size,
                              hipStream_t stream)
{
  (void)in_sizes; (void)n_in; (void)out_size; (void)ws_size;
  const float* msa        = (const float*)d_in[0];
  const float* pair       = (const float*)d_in[1];
  const float* ln_m_scale = (const float*)d_in[2];
  const float* ln_m_bias  = (const float*)d_in[3];
  const float* ln_z_scale = (const float*)d_in[4];
  const float* ln_z_bias  = (const float*)d_in[5];
  const float* w_q        = (const float*)d_in[6];
  const float* w_k        = (const float*)d_in[7];
  const float* w_v        = (const float*)d_in[8];
  const float* w_b        = (const float*)d_in[9];
  const float* w_out      = (const float*)d_in[10];
  const float* b_out      = (const float*)d_in[11];
  const float* w_gate     = (const float*)d_in[12];
  const float* b_gate     = (const float*)d_in[13];

  char* ws = (char*)d_ws;
  u16*   m_bf    = (u16*)(ws);                   // 32768*256 bf16   = 16 MB
  u16*   wobf    = (u16*)(ws + 16777216);        // 128 KB
  u16*   wfrag   = (u16*)(ws + 16908288);        // 512 KB
  u16*   gatebh  = (u16*)(ws + 17432576);        // 16 MB
  u16*   biasQ   = (u16*)(ws + 34209792);        // 1 MB
  u16*   attn_oh = (u16*)(ws + 35258368);        // 16 MB
  float* out = (float*)d_out;

  pre_kernel<<<dim3(9792), dim3(256), 0, stream>>>(
      msa, ln_m_scale, ln_m_bias, m_bf, w_q, w_k, w_v, w_gate, w_out, wfrag, wobf,
      pair, ln_z_scale, ln_z_bias, w_b, biasQ);
  qkv_attn_kernel<<<dim3(1024), dim3(512), 0, stream>>>(
      m_bf, wfrag, b_gate, biasQ, gatebh, attn_oh);
  gemm_epi1<<<dim3(512), dim3(512), 0, stream>>>(attn_oh, wobf, gatebh, out, msa, b_out);
}